// Round 12
// baseline (179.670 us; speedup 1.0000x reference)
//
#include <hip/hip_runtime.h>

#define NB 4
#define NPRI 3106
#define NC 21
#define NCLS 20
#define KMAX 200
#define NMAX 1024   /* candidate capacity per (image,class) */
#define WMAX 16     /* NMAX/64 */
#define T2MAX 72    /* 128x64 tiles: sum_{w2=0}^{7} (16-2*w2) */
#define MIN_SC 0.05f
#define MAX_OV 0.45f

/* ---- workspace layout (float-element offsets; u64 arrays at even offsets) ---- */
#define F_PROBS 0                                  /* NB*NCLS*NPRI floats, [b][cls-1][p] */
#define F_KEYS  (F_PROBS + NB*NCLS*NPRI)           /* NB*NCLS*NMAX u64 (sorted keys)     */
#define F_BOXES (F_KEYS + NB*NCLS*NMAX*2)          /* NB*NCLS*NMAX float4 (sorted boxes) */
#define F_AREAS (F_BOXES + NB*NCLS*NMAX*4)         /* NB*NCLS*NMAX floats                */
#define F_NCAND (F_AREAS + NB*NCLS*NMAX)           /* NB*NCLS ints (pad to 128)          */
#define F_M     (F_NCAND + 128)                    /* NB*NCLS*WMAX*NMAX u64, [bc][w][j]  */
#define F_POOL  (F_M + NB*NCLS*WMAX*NMAX*2)        /* NB*NCLS*KMAX u64                   */
#define F_CNT   (F_POOL + NB*NCLS*KMAX*2)          /* NB*NCLS ints                       */
#define F_DONE  (F_CNT + NB*NCLS)                  /* NB ints (per-image done counters)  */

/* ---- output layout (floats) ---- */
#define OUT_BOXES  0
#define OUT_LABELS (NB*KMAX*4)
#define OUT_SCORES (OUT_LABELS + NB*KMAX)
#define OUT_COUNTS (OUT_SCORES + NB*KMAX)

__device__ __forceinline__ float bcast(float v, int l) {
    return __uint_as_float(__builtin_amdgcn_readlane(__float_as_uint(v), l));
}

__device__ __forceinline__ void decode_box(const float* __restrict__ locs,
                                           const float* __restrict__ priors,
                                           int b, int pi,
                                           float& x1, float& y1, float& x2, float& y2) {
    const float* l  = locs + ((size_t)b * NPRI + pi) * 4;
    const float* pr = priors + (size_t)pi * 4;
    float pcx = pr[0], pcy = pr[1], pw = pr[2], ph = pr[3];
    /* reference op order: (l*pw)/10 + pcx ; exp(l/5)*pw ; cx -/+ w/2 */
    float cx = l[0] * pw / 10.0f + pcx;
    float cy = l[1] * ph / 10.0f + pcy;
    float w  = expf(l[2] / 5.0f) * pw;
    float h  = expf(l[3] / 5.0f) * ph;
    x1 = cx - w / 2.0f;  y1 = cy - h / 2.0f;
    x2 = cx + w / 2.0f;  y2 = cy + h / 2.0f;
}

/* K0: softmax once per (b,p); coalesced stage via LDS (proven verbatim) */
__global__ __launch_bounds__(256)
void det_softmax(const float* __restrict__ scores, float* __restrict__ ws) {
    __shared__ float row[256 * NC];
    const int t0 = blockIdx.x * 256;
    int items = NB * NPRI - t0; if (items > 256) items = 256;
    const int cntf = items * NC;
    for (int i = threadIdx.x; i < cntf; i += 256)
        row[i] = scores[(size_t)t0 * NC + i];
    __syncthreads();
    const int t = t0 + threadIdx.x;
    if (t >= NB * NPRI) return;
    const int b = t / NPRI, p = t - b * NPRI;
    const float* s = row + threadIdx.x * NC;
    float m = -1e30f;
    #pragma unroll
    for (int c = 0; c < NC; ++c) m = fmaxf(m, s[c]);
    float e[NC]; float sum = 0.0f;
    #pragma unroll
    for (int c = 0; c < NC; ++c) { e[c] = expf(s[c] - m); sum += e[c]; }
    #pragma unroll
    for (int c = 1; c < NC; ++c)
        ws[F_PROBS + ((size_t)(b * NCLS + (c - 1)) * NPRI + p)] = e[c] / sum;
}

/* K1: per (image,class): compact > 0.05, bitonic sort, decode (proven verbatim) */
__global__ __launch_bounds__(256)
void det_prep(const float* __restrict__ locs, const float* __restrict__ priors,
              float* __restrict__ ws) {
    const int bc  = blockIdx.x;
    const int b   = bc / NCLS;
    const int tid = threadIdx.x;

    __shared__ unsigned long long keys[NMAX];   /* 8 KB */
    __shared__ int n_sh;
    if (tid == 0) n_sh = 0;
    __syncthreads();

    const float* prob = ws + F_PROBS + (size_t)bc * NPRI;
    for (int p = tid; p < NPRI; p += 256) {
        float s = prob[p];
        if (s > MIN_SC) {
            int idx = atomicAdd(&n_sh, 1);
            if (idx < NMAX) {
                unsigned int sb = __float_as_uint(s);
                keys[idx] = ((unsigned long long)(~sb) << 32) | (unsigned int)p;
            }
        }
    }
    __syncthreads();
    int n = n_sh; if (n > NMAX) n = NMAX;

    int npow = 1; while (npow < n) npow <<= 1;
    for (int i = n + tid; i < npow; i += 256) keys[i] = ~0ull;
    for (int k = 2; k <= npow; k <<= 1) {
        for (int j = k >> 1; j > 0; j >>= 1) {
            __syncthreads();
            for (int i = tid; i < npow; i += 256) {
                int ixj = i ^ j;
                if (ixj > i) {
                    unsigned long long a = keys[i], d = keys[ixj];
                    bool up = ((i & k) == 0);
                    if ((a > d) == up) { keys[i] = d; keys[ixj] = a; }
                }
            }
        }
    }
    __syncthreads();

    if (tid == 0) ((int*)(ws + F_NCAND))[bc] = n;
    unsigned long long* gk = (unsigned long long*)(ws + F_KEYS) + (size_t)bc * NMAX;
    float4* gb = (float4*)(ws + F_BOXES) + (size_t)bc * NMAX;
    float*  ga = ws + F_AREAS + (size_t)bc * NMAX;
    for (int i = tid; i < n; i += 256) {
        unsigned long long k = keys[i];
        gk[i] = k;
        int pi = (int)(k & 0xFFFFFFFFull);
        float x1, y1, x2, y2;
        decode_box(locs, priors, b, pi, x1, y1, x2, y2);
        gb[i] = make_float4(x1, y1, x2, y2);
        ga[i] = (x2 - x1) * (y2 - y1);
    }
}

/* K2 v4: 128x64 tile per wave. Lane holds TWO i-boxes (words 2w2, 2w2+1) and
   its j-box; per 2-column broadcast (10 readlanes) computes 4 independent IoU
   chains. Divide-free with exact-div near band (bit-identical M). Hi word is
   never read by resolve when tj==2w2 (word > column's word) -> not stored.
   Tile space: (w2, tj) with tj >= 2*w2, flattened to 72 tiles. */
__global__ __launch_bounds__(256)
void det_mbuild(float* __restrict__ ws) {
    if (blockIdx.x == 0 && blockIdx.y == 0 && threadIdx.x < NB)
        ((int*)(ws + F_DONE))[threadIdx.x] = 0;

    const int bc = blockIdx.y;
    const int t  = blockIdx.x * 4 + (threadIdx.x >> 6);
    if (t >= T2MAX) return;
    const int lane = threadIdx.x & 63;
    int w2 = 0, off = 0;
    while (off + (16 - 2 * w2) <= t) { off += 16 - 2 * w2; ++w2; }  /* uniform */
    const int tj = 2 * w2 + (t - off);            /* tj in [2*w2, 16) */
    const int n = ((const int*)(ws + F_NCAND))[bc];
    const int i0 = w2 * 128, bj0 = tj * 64;
    if (bj0 >= n) return;

    const float4* bx = (const float4*)(ws + F_BOXES) + (size_t)bc * NMAX;
    const float*  ar = ws + F_AREAS + (size_t)bc * NMAX;
    const float4 bl = bx[i0 + lane];        /* i-word lo */
    const float  al = ar[i0 + lane];
    const float4 bh = bx[i0 + 64 + lane];   /* i-word hi */
    const float  ah = ar[i0 + 64 + lane];
    const float4 bj = bx[bj0 + lane];
    const float  aj = ar[bj0 + lane];

    const int rem_lo = n - i0;
    const int rem_hi = n - (i0 + 64);
    const unsigned long long vm_lo =
        rem_lo >= 64 ? ~0ull : ((1ull << rem_lo) - 1ull);
    const unsigned long long vm_hi =
        rem_hi >= 64 ? ~0ull : (rem_hi <= 0 ? 0ull : ((1ull << rem_hi) - 1ull));
    const bool diag_lo = (tj == 2 * w2);
    const bool diag_hi = (tj == 2 * w2 + 1);
    unsigned long long mw_lo = 0ull, mw_hi = 0ull;

    #pragma unroll
    for (int jj = 0; jj < 64; jj += 2) {
        float ax1 = bcast(bj.x, jj),     ay1 = bcast(bj.y, jj);
        float ax2 = bcast(bj.z, jj),     ay2 = bcast(bj.w, jj);
        float aau = bcast(aj, jj);
        float cx1 = bcast(bj.x, jj + 1), cy1 = bcast(bj.y, jj + 1);
        float cx2 = bcast(bj.z, jj + 1), cy2 = bcast(bj.w, jj + 1);
        float cau = bcast(aj, jj + 1);

        /* 4 independent chains: (lo,A) (lo,C) (hi,A) (hi,C) */
        float laA = fmaxf(bl.x, ax1), lbA = fmaxf(bl.y, ay1);
        float raA = fminf(bl.z, ax2), rbA = fminf(bl.w, ay2);
        float laC = fmaxf(bl.x, cx1), lbC = fmaxf(bl.y, cy1);
        float raC = fminf(bl.z, cx2), rbC = fminf(bl.w, cy2);
        float haA = fmaxf(bh.x, ax1), hbA = fmaxf(bh.y, ay1);
        float gaA = fminf(bh.z, ax2), gbA = fminf(bh.w, ay2);
        float haC = fmaxf(bh.x, cx1), hbC = fmaxf(bh.y, cy1);
        float gaC = fminf(bh.z, cx2), gbC = fminf(bh.w, cy2);

        float inLA = fmaxf(raA - laA, 0.0f) * fmaxf(rbA - lbA, 0.0f);
        float inLC = fmaxf(raC - laC, 0.0f) * fmaxf(rbC - lbC, 0.0f);
        float inHA = fmaxf(gaA - haA, 0.0f) * fmaxf(gbA - hbA, 0.0f);
        float inHC = fmaxf(gaC - haC, 0.0f) * fmaxf(gbC - hbC, 0.0f);

        float uLA = al + aau - inLA,  tLA = MAX_OV * uLA;
        float uLC = al + cau - inLC,  tLC = MAX_OV * uLC;
        float uHA = ah + aau - inHA,  tHA = MAX_OV * uHA;
        float uHC = ah + cau - inHC,  tHC = MAX_OV * uHC;

        bool kLA = inLA > tLA, kLC = inLC > tLC;
        bool kHA = inHA > tHA, kHC = inHC > tHC;
        bool nLA = fabsf(inLA - tLA) <= tLA * 6e-7f;
        bool nLC = fabsf(inLC - tLC) <= tLC * 6e-7f;
        bool nHA = fabsf(inHA - tHA) <= tHA * 6e-7f;
        bool nHC = fabsf(inHC - tHC) <= tHC * 6e-7f;
        if (__ballot((nLA || nLC) || (nHA || nHC))) {  /* rare exact-div path */
            kLA = nLA ? (inLA / uLA > MAX_OV) : kLA;
            kLC = nLC ? (inLC / uLC > MAX_OV) : kLC;
            kHA = nHA ? (inHA / uHA > MAX_OV) : kHA;
            kHC = nHC ? (inHC / uHC > MAX_OV) : kHC;
        }

        unsigned long long a0 = __ballot(kLA) & vm_lo;
        unsigned long long c0 = __ballot(kLC) & vm_lo;
        unsigned long long a1 = __ballot(kHA) & vm_hi;
        unsigned long long c1 = __ballot(kHC) & vm_hi;
        if (diag_lo) {                       /* i<j masking on diagonal word */
            a0 &= (1ull << jj) - 1ull;
            c0 &= (1ull << (jj + 1)) - 1ull;
        }
        if (diag_hi) {
            a1 &= (1ull << jj) - 1ull;
            c1 &= (1ull << (jj + 1)) - 1ull;
        }
        if (lane == jj)     { mw_lo = a0; mw_hi = a1; }
        if (lane == jj + 1) { mw_lo = c0; mw_hi = c1; }
    }

    if (bj0 + lane < n) {
        unsigned long long* Mp =
            (unsigned long long*)(ws + F_M) + (size_t)bc * WMAX * NMAX;
        Mp[(size_t)(2 * w2) * NMAX + bj0 + lane] = mw_lo;
        if (!diag_lo)   /* hi word only read when its word index <= tj */
            Mp[(size_t)(2 * w2 + 1) * NMAX + bj0 + lane] = mw_hi;
    }
}

/* K3: resolve (wave 0 of 80 blocks) + zero-fill + release/acquire via done[b],
   then round-7 per-class rank-select topk (round-11 proven, verbatim). */
__global__ __launch_bounds__(256)
void det_finish(const float* __restrict__ locs, const float* __restrict__ priors,
                float* __restrict__ ws, float* __restrict__ out) {
    const int bc   = blockIdx.x;
    const int b    = bc / NCLS;
    const int c    = bc - b * NCLS;       /* 0..19 */
    const int cls  = c + 1;
    const int tid  = threadIdx.x;
    int* done_i = (int*)(ws + F_DONE);

    if (tid < 64) {
        const int lane = tid;
        const int n    = ((const int*)(ws + F_NCAND))[bc];
        const unsigned long long* Mb =
            (const unsigned long long*)(ws + F_M) + (size_t)bc * WMAX * NMAX;

        unsigned long long kw[WMAX];
        #pragma unroll
        for (int w = 0; w < WMAX; ++w) kw[w] = 0ull;

        const unsigned long long lmask = (1ull << lane) - 1ull;
        #pragma unroll
        for (int w = 0; w < WMAX; ++w) {
            if (w * 64 < n) {
                int cc = w * 64 + lane;
                bool valid = cc < n;
                unsigned long long pre = 0ull;
                #pragma unroll
                for (int v = 0; v < WMAX; ++v)
                    if (v < w) pre |= Mb[(size_t)v * NMAX + cc] & kw[v];
                unsigned long long dg = Mb[(size_t)w * NMAX + cc] & lmask;
                bool sup0 = (pre != 0ull);
                unsigned long long K = __ballot(valid && !sup0);
                for (int it = 0; it < 64; ++it) {
                    bool sup = sup0 || ((dg & K) != 0ull);
                    unsigned long long Kn = __ballot(valid && !sup);
                    if (Kn == K) break;
                    K = Kn;
                }
                kw[w] = K;
            }
        }

        int pref[WMAX + 1];
        pref[0] = 0;
        #pragma unroll
        for (int w = 0; w < WMAX; ++w) pref[w + 1] = pref[w] + __popcll(kw[w]);
        if (lane == 0) ((int*)(ws + F_CNT))[bc] = pref[WMAX];

        const unsigned long long* gk =
            (const unsigned long long*)(ws + F_KEYS) + (size_t)bc * NMAX;
        unsigned long long* pool =
            (unsigned long long*)(ws + F_POOL) + (size_t)bc * KMAX;
        const unsigned long long ctag = (unsigned long long)(cls << 12);
        #pragma unroll
        for (int w = 0; w < WMAX; ++w) {
            unsigned long long kwv = kw[w];
            int cc = w * 64 + lane;
            if (cc < n && ((kwv >> lane) & 1ull)) {
                int pos = pref[w] + __popcll(kwv & lmask);
                if (pos < KMAX) pool[pos] = gk[cc] | ctag;
            }
        }
    }

    /* zero image b's output slice, partitioned over its 20 blocks */
    {
        int idx = c * 256 + tid;
        if (idx < KMAX * 4) {
            out[OUT_BOXES + (size_t)b * KMAX * 4 + idx] = 0.0f;
        } else if (idx < KMAX * 4 + KMAX) {
            out[OUT_LABELS + b * KMAX + (idx - KMAX * 4)] = 0.0f;
        } else if (idx < KMAX * 4 + 2 * KMAX) {
            out[OUT_SCORES + b * KMAX + (idx - KMAX * 4 - KMAX)] = 0.0f;
        }
    }

    __threadfence();
    __syncthreads();
    if (tid == 0)
        __hip_atomic_fetch_add(done_i + b, 1, __ATOMIC_RELEASE,
                               __HIP_MEMORY_SCOPE_AGENT);

    if (tid == 0) {
        int it = 0;
        while (__hip_atomic_load(done_i + b, __ATOMIC_ACQUIRE,
                                 __HIP_MEMORY_SCOPE_AGENT) < NCLS
               && it < (1 << 20)) ++it;
    }
    __syncthreads();

    __shared__ unsigned long long lpool[NCLS * KMAX];  /* 32 KB */
    __shared__ int cnts[NCLS];

    const int* cnt = (const int*)(ws + F_CNT);
    if (tid < NCLS) cnts[tid] = cnt[b * NCLS + tid];
    __syncthreads();

    const unsigned long long* pool =
        (const unsigned long long*)(ws + F_POOL) + (size_t)b * NCLS * KMAX;
    for (int i = tid; i < NCLS * KMAX; i += 256) {
        int c2 = i / KMAX, r = i - c2 * KMAX;
        int mc2 = cnts[c2] < KMAX ? cnts[c2] : KMAX;
        lpool[i] = (r < mc2) ? pool[i] : ~0ull;
    }
    __syncthreads();

    if (c == 0 && tid == 0) {
        int tot = 0;
        for (int c2 = 0; c2 < NCLS; ++c2) tot += cnts[c2];
        int count = tot < KMAX ? tot : KMAX;
        if (tot == 0) {
            float* ob = out + OUT_BOXES + (size_t)b * KMAX * 4;
            ob[0] = 0.0f; ob[1] = 0.0f; ob[2] = 1.0f; ob[3] = 1.0f;
            count = 1;
        }
        out[OUT_COUNTS + b] = (float)count;
    }

    const int mc = cnts[c] < KMAX ? cnts[c] : KMAX;
    if (tid < mc) {
        unsigned long long key = lpool[c * KMAX + tid];
        int rank = 0;
        #pragma unroll
        for (int c2 = 0; c2 < NCLS; ++c2) {
            int lo = 0, hi = KMAX;
            #pragma unroll
            for (int s = 0; s < 8; ++s) {          /* ceil(log2(201)) = 8 */
                int mid = (lo + hi) >> 1;
                int midc = mid < KMAX ? mid : KMAX - 1;
                unsigned long long v = lpool[c2 * KMAX + midc];
                bool lt = (lo < hi) && (v < key);
                lo = lt ? mid + 1 : lo;
                hi = lt ? hi : mid;
            }
            rank += lo;
        }
        if (rank < KMAX) {
            unsigned int lo32 = (unsigned int)key;
            int pi  = lo32 & 0xFFF;
            int lab = (lo32 >> 12) & 0x1F;
            float sc = __uint_as_float(~(unsigned int)(key >> 32));
            float x1, y1, x2, y2;
            decode_box(locs, priors, b, pi, x1, y1, x2, y2);
            float* ob = out + OUT_BOXES + ((size_t)b * KMAX + rank) * 4;
            ob[0] = x1; ob[1] = y1; ob[2] = x2; ob[3] = y2;
            out[OUT_LABELS + b * KMAX + rank] = (float)lab;
            out[OUT_SCORES + b * KMAX + rank] = sc;
        }
    }
}

extern "C" void kernel_launch(void* const* d_in, const int* in_sizes, int n_in,
                              void* d_out, int out_size, void* d_ws, size_t ws_size,
                              hipStream_t stream) {
    const float* locs   = (const float*)d_in[0];
    const float* scores = (const float*)d_in[1];
    const float* priors = (const float*)d_in[2];
    float* out = (float*)d_out;
    float* ws  = (float*)d_ws;

    det_softmax<<<(NB * NPRI + 255) / 256, 256, 0, stream>>>(scores, ws);
    det_prep<<<NB * NCLS, 256, 0, stream>>>(locs, priors, ws);
    det_mbuild<<<dim3((T2MAX + 3) / 4, NB * NCLS), 256, 0, stream>>>(ws);
    det_finish<<<NB * NCLS, 256, 0, stream>>>(locs, priors, ws, out);
}

// Round 13
// 178.437 us; speedup vs baseline: 1.0069x; 1.0069x over previous
//
#include <hip/hip_runtime.h>

#define NB 4
#define NPRI 3106
#define NC 21
#define NCLS 20
#define KMAX 200
#define NMAX 1024   /* candidate capacity per (image,class) */
#define WMAX 16     /* NMAX/64 */
#define TMAX (WMAX*(WMAX+1)/2)   /* 136 triangular 64x64 tiles */
#define MIN_SC 0.05f
#define MAX_OV 0.45f

/* ---- workspace layout (float-element offsets; u64 arrays at even offsets) ---- */
#define F_PROBS 0                                  /* NB*NCLS*NPRI floats, [b][cls-1][p] */
#define F_KEYS  (F_PROBS + NB*NCLS*NPRI)           /* NB*NCLS*NMAX u64 (sorted keys)     */
#define F_BOXES (F_KEYS + NB*NCLS*NMAX*2)          /* NB*NCLS*NMAX float4 (sorted boxes) */
#define F_AREAS (F_BOXES + NB*NCLS*NMAX*4)         /* NB*NCLS*NMAX floats                */
#define F_NCAND (F_AREAS + NB*NCLS*NMAX)           /* NB*NCLS ints (pad to 128)          */
#define F_M     (F_NCAND + 128)                    /* NB*NCLS*WMAX*NMAX u64, [bc][w][j]  */
#define F_POOL  (F_M + NB*NCLS*WMAX*NMAX*2)        /* NB*NCLS*KMAX u64                   */
#define F_CNT   (F_POOL + NB*NCLS*KMAX*2)          /* NB*NCLS ints                       */
#define F_DONE  (F_CNT + NB*NCLS)                  /* NB ints (per-image done counters)  */

/* ---- output layout (floats) ---- */
#define OUT_BOXES  0
#define OUT_LABELS (NB*KMAX*4)
#define OUT_SCORES (OUT_LABELS + NB*KMAX)
#define OUT_COUNTS (OUT_SCORES + NB*KMAX)

__device__ __forceinline__ float bcast(float v, int l) {
    return __uint_as_float(__builtin_amdgcn_readlane(__float_as_uint(v), l));
}

__device__ __forceinline__ void decode_box(const float* __restrict__ locs,
                                           const float* __restrict__ priors,
                                           int b, int pi,
                                           float& x1, float& y1, float& x2, float& y2) {
    const float* l  = locs + ((size_t)b * NPRI + pi) * 4;
    const float* pr = priors + (size_t)pi * 4;
    float pcx = pr[0], pcy = pr[1], pw = pr[2], ph = pr[3];
    /* reference op order: (l*pw)/10 + pcx ; exp(l/5)*pw ; cx -/+ w/2 */
    float cx = l[0] * pw / 10.0f + pcx;
    float cy = l[1] * ph / 10.0f + pcy;
    float w  = expf(l[2] / 5.0f) * pw;
    float h  = expf(l[3] / 5.0f) * ph;
    x1 = cx - w / 2.0f;  y1 = cy - h / 2.0f;
    x2 = cx + w / 2.0f;  y2 = cy + h / 2.0f;
}

/* K0: softmax once per (b,p); coalesced stage via LDS (proven verbatim) */
__global__ __launch_bounds__(256)
void det_softmax(const float* __restrict__ scores, float* __restrict__ ws) {
    __shared__ float row[256 * NC];
    const int t0 = blockIdx.x * 256;
    int items = NB * NPRI - t0; if (items > 256) items = 256;
    const int cntf = items * NC;
    for (int i = threadIdx.x; i < cntf; i += 256)
        row[i] = scores[(size_t)t0 * NC + i];
    __syncthreads();
    const int t = t0 + threadIdx.x;
    if (t >= NB * NPRI) return;
    const int b = t / NPRI, p = t - b * NPRI;
    const float* s = row + threadIdx.x * NC;
    float m = -1e30f;
    #pragma unroll
    for (int c = 0; c < NC; ++c) m = fmaxf(m, s[c]);
    float e[NC]; float sum = 0.0f;
    #pragma unroll
    for (int c = 0; c < NC; ++c) { e[c] = expf(s[c] - m); sum += e[c]; }
    #pragma unroll
    for (int c = 1; c < NC; ++c)
        ws[F_PROBS + ((size_t)(b * NCLS + (c - 1)) * NPRI + p)] = e[c] / sum;
}

/* K1: per (image,class): compact > 0.05, bitonic sort, decode (proven verbatim) */
__global__ __launch_bounds__(256)
void det_prep(const float* __restrict__ locs, const float* __restrict__ priors,
              float* __restrict__ ws) {
    const int bc  = blockIdx.x;
    const int b   = bc / NCLS;
    const int tid = threadIdx.x;

    __shared__ unsigned long long keys[NMAX];   /* 8 KB */
    __shared__ int n_sh;
    if (tid == 0) n_sh = 0;
    __syncthreads();

    const float* prob = ws + F_PROBS + (size_t)bc * NPRI;
    for (int p = tid; p < NPRI; p += 256) {
        float s = prob[p];
        if (s > MIN_SC) {
            int idx = atomicAdd(&n_sh, 1);
            if (idx < NMAX) {
                unsigned int sb = __float_as_uint(s);
                keys[idx] = ((unsigned long long)(~sb) << 32) | (unsigned int)p;
            }
        }
    }
    __syncthreads();
    int n = n_sh; if (n > NMAX) n = NMAX;

    int npow = 1; while (npow < n) npow <<= 1;
    for (int i = n + tid; i < npow; i += 256) keys[i] = ~0ull;
    for (int k = 2; k <= npow; k <<= 1) {
        for (int j = k >> 1; j > 0; j >>= 1) {
            __syncthreads();
            for (int i = tid; i < npow; i += 256) {
                int ixj = i ^ j;
                if (ixj > i) {
                    unsigned long long a = keys[i], d = keys[ixj];
                    bool up = ((i & k) == 0);
                    if ((a > d) == up) { keys[i] = d; keys[ixj] = a; }
                }
            }
        }
    }
    __syncthreads();

    if (tid == 0) ((int*)(ws + F_NCAND))[bc] = n;
    unsigned long long* gk = (unsigned long long*)(ws + F_KEYS) + (size_t)bc * NMAX;
    float4* gb = (float4*)(ws + F_BOXES) + (size_t)bc * NMAX;
    float*  ga = ws + F_AREAS + (size_t)bc * NMAX;
    for (int i = tid; i < n; i += 256) {
        unsigned long long k = keys[i];
        gk[i] = k;
        int pi = (int)(k & 0xFFFFFFFFull);
        float x1, y1, x2, y2;
        decode_box(locs, priors, b, pi, x1, y1, x2, y2);
        gb[i] = make_float4(x1, y1, x2, y2);
        ga[i] = (x2 - x1) * (y2 - y1);
    }
}

/* K2 v5: round-11 64x64 tile structure (136 tiles — occupancy proven) with
   FOUR independent column-chains per unrolled step (ILP within the wave).
   Divide-free with exact-div near band -> bit-identical M to rounds 9-12. */
__global__ __launch_bounds__(256)
void det_mbuild(float* __restrict__ ws) {
    if (blockIdx.x == 0 && blockIdx.y == 0 && threadIdx.x < NB)
        ((int*)(ws + F_DONE))[threadIdx.x] = 0;

    const int bc = blockIdx.y;
    const int t  = blockIdx.x * 4 + (threadIdx.x >> 6);
    if (t >= TMAX) return;
    const int lane = threadIdx.x & 63;
    int tj = 0;
    while ((tj + 1) * (tj + 2) / 2 <= t) ++tj;   /* wave-uniform decode */
    const int w = t - tj * (tj + 1) / 2;          /* w <= tj */
    const int n = ((const int*)(ws + F_NCAND))[bc];
    const int bi0 = w * 64, bj0 = tj * 64;
    if (bj0 >= n) return;

    const float4* bx = (const float4*)(ws + F_BOXES) + (size_t)bc * NMAX;
    const float*  ar = ws + F_AREAS + (size_t)bc * NMAX;
    const float4 bi = bx[bi0 + lane];
    const float  ai = ar[bi0 + lane];
    const float4 bj = bx[bj0 + lane];
    const float  aj = ar[bj0 + lane];
    const unsigned long long vm =
        (n - bi0 >= 64) ? ~0ull : ((1ull << (n - bi0)) - 1ull);
    const bool diag = (w == tj);
    unsigned long long myword = 0ull;

    #pragma unroll
    for (int jj = 0; jj < 64; jj += 4) {
        float jx1[4], jy1[4], jx2[4], jy2[4], jau[4];
        #pragma unroll
        for (int k = 0; k < 4; ++k) {
            jx1[k] = bcast(bj.x, jj + k);
            jy1[k] = bcast(bj.y, jj + k);
            jx2[k] = bcast(bj.z, jj + k);
            jy2[k] = bcast(bj.w, jj + k);
            jau[k] = bcast(aj,   jj + k);
        }
        bool keep[4], nearb[4];
        float inters[4], uni[4];
        #pragma unroll
        for (int k = 0; k < 4; ++k) {
            float lx = fmaxf(bi.x, jx1[k]), ly = fmaxf(bi.y, jy1[k]);
            float rx = fminf(bi.z, jx2[k]), ry = fminf(bi.w, jy2[k]);
            float dx = fmaxf(rx - lx, 0.0f), dy = fmaxf(ry - ly, 0.0f);
            float inter = dx * dy;
            float u  = ai + jau[k] - inter;     /* union > 0 (areas positive) */
            float th = MAX_OV * u;
            inters[k] = inter; uni[k] = u;
            keep[k]  = inter > th;
            nearb[k] = fabsf(inter - th) <= th * 6e-7f;
        }
        if (__ballot((nearb[0] || nearb[1]) || (nearb[2] || nearb[3]))) {
            #pragma unroll
            for (int k = 0; k < 4; ++k)          /* rare: exact ref-order div */
                if (nearb[k]) keep[k] = (inters[k] / uni[k]) > MAX_OV;
        }
        #pragma unroll
        for (int k = 0; k < 4; ++k) {
            unsigned long long bits = __ballot(keep[k]) & vm;
            if (diag) bits &= (1ull << (jj + k)) - 1ull;   /* i<j on diagonal */
            if (lane == jj + k) myword = bits;
        }
    }
    if (bj0 + lane < n)
        ((unsigned long long*)(ws + F_M))
            [((size_t)bc * WMAX + w) * NMAX + bj0 + lane] = myword;
}

/* K3: resolve (wave 0 of 80 blocks) + zero-fill + release/acquire via done[b],
   then round-7 per-class rank-select topk (round-11 proven, verbatim). */
__global__ __launch_bounds__(256)
void det_finish(const float* __restrict__ locs, const float* __restrict__ priors,
                float* __restrict__ ws, float* __restrict__ out) {
    const int bc   = blockIdx.x;
    const int b    = bc / NCLS;
    const int c    = bc - b * NCLS;       /* 0..19 */
    const int cls  = c + 1;
    const int tid  = threadIdx.x;
    int* done_i = (int*)(ws + F_DONE);

    if (tid < 64) {
        const int lane = tid;
        const int n    = ((const int*)(ws + F_NCAND))[bc];
        const unsigned long long* Mb =
            (const unsigned long long*)(ws + F_M) + (size_t)bc * WMAX * NMAX;

        unsigned long long kw[WMAX];
        #pragma unroll
        for (int w = 0; w < WMAX; ++w) kw[w] = 0ull;

        const unsigned long long lmask = (1ull << lane) - 1ull;
        #pragma unroll
        for (int w = 0; w < WMAX; ++w) {
            if (w * 64 < n) {
                int cc = w * 64 + lane;
                bool valid = cc < n;
                unsigned long long pre = 0ull;
                #pragma unroll
                for (int v = 0; v < WMAX; ++v)
                    if (v < w) pre |= Mb[(size_t)v * NMAX + cc] & kw[v];
                unsigned long long dg = Mb[(size_t)w * NMAX + cc] & lmask;
                bool sup0 = (pre != 0ull);
                unsigned long long K = __ballot(valid && !sup0);
                for (int it = 0; it < 64; ++it) {
                    bool sup = sup0 || ((dg & K) != 0ull);
                    unsigned long long Kn = __ballot(valid && !sup);
                    if (Kn == K) break;
                    K = Kn;
                }
                kw[w] = K;
            }
        }

        int pref[WMAX + 1];
        pref[0] = 0;
        #pragma unroll
        for (int w = 0; w < WMAX; ++w) pref[w + 1] = pref[w] + __popcll(kw[w]);
        if (lane == 0) ((int*)(ws + F_CNT))[bc] = pref[WMAX];

        const unsigned long long* gk =
            (const unsigned long long*)(ws + F_KEYS) + (size_t)bc * NMAX;
        unsigned long long* pool =
            (unsigned long long*)(ws + F_POOL) + (size_t)bc * KMAX;
        const unsigned long long ctag = (unsigned long long)(cls << 12);
        #pragma unroll
        for (int w = 0; w < WMAX; ++w) {
            unsigned long long kwv = kw[w];
            int cc = w * 64 + lane;
            if (cc < n && ((kwv >> lane) & 1ull)) {
                int pos = pref[w] + __popcll(kwv & lmask);
                if (pos < KMAX) pool[pos] = gk[cc] | ctag;
            }
        }
    }

    /* zero image b's output slice, partitioned over its 20 blocks */
    {
        int idx = c * 256 + tid;
        if (idx < KMAX * 4) {
            out[OUT_BOXES + (size_t)b * KMAX * 4 + idx] = 0.0f;
        } else if (idx < KMAX * 4 + KMAX) {
            out[OUT_LABELS + b * KMAX + (idx - KMAX * 4)] = 0.0f;
        } else if (idx < KMAX * 4 + 2 * KMAX) {
            out[OUT_SCORES + b * KMAX + (idx - KMAX * 4 - KMAX)] = 0.0f;
        }
    }

    __threadfence();
    __syncthreads();
    if (tid == 0)
        __hip_atomic_fetch_add(done_i + b, 1, __ATOMIC_RELEASE,
                               __HIP_MEMORY_SCOPE_AGENT);

    if (tid == 0) {
        int it = 0;
        while (__hip_atomic_load(done_i + b, __ATOMIC_ACQUIRE,
                                 __HIP_MEMORY_SCOPE_AGENT) < NCLS
               && it < (1 << 20)) ++it;
    }
    __syncthreads();

    __shared__ unsigned long long lpool[NCLS * KMAX];  /* 32 KB */
    __shared__ int cnts[NCLS];

    const int* cnt = (const int*)(ws + F_CNT);
    if (tid < NCLS) cnts[tid] = cnt[b * NCLS + tid];
    __syncthreads();

    const unsigned long long* pool =
        (const unsigned long long*)(ws + F_POOL) + (size_t)b * NCLS * KMAX;
    for (int i = tid; i < NCLS * KMAX; i += 256) {
        int c2 = i / KMAX, r = i - c2 * KMAX;
        int mc2 = cnts[c2] < KMAX ? cnts[c2] : KMAX;
        lpool[i] = (r < mc2) ? pool[i] : ~0ull;
    }
    __syncthreads();

    if (c == 0 && tid == 0) {
        int tot = 0;
        for (int c2 = 0; c2 < NCLS; ++c2) tot += cnts[c2];
        int count = tot < KMAX ? tot : KMAX;
        if (tot == 0) {
            float* ob = out + OUT_BOXES + (size_t)b * KMAX * 4;
            ob[0] = 0.0f; ob[1] = 0.0f; ob[2] = 1.0f; ob[3] = 1.0f;
            count = 1;
        }
        out[OUT_COUNTS + b] = (float)count;
    }

    const int mc = cnts[c] < KMAX ? cnts[c] : KMAX;
    if (tid < mc) {
        unsigned long long key = lpool[c * KMAX + tid];
        int rank = 0;
        #pragma unroll
        for (int c2 = 0; c2 < NCLS; ++c2) {
            int lo = 0, hi = KMAX;
            #pragma unroll
            for (int s = 0; s < 8; ++s) {          /* ceil(log2(201)) = 8 */
                int mid = (lo + hi) >> 1;
                int midc = mid < KMAX ? mid : KMAX - 1;
                unsigned long long v = lpool[c2 * KMAX + midc];
                bool lt = (lo < hi) && (v < key);
                lo = lt ? mid + 1 : lo;
                hi = lt ? hi : mid;
            }
            rank += lo;
        }
        if (rank < KMAX) {
            unsigned int lo32 = (unsigned int)key;
            int pi  = lo32 & 0xFFF;
            int lab = (lo32 >> 12) & 0x1F;
            float sc = __uint_as_float(~(unsigned int)(key >> 32));
            float x1, y1, x2, y2;
            decode_box(locs, priors, b, pi, x1, y1, x2, y2);
            float* ob = out + OUT_BOXES + ((size_t)b * KMAX + rank) * 4;
            ob[0] = x1; ob[1] = y1; ob[2] = x2; ob[3] = y2;
            out[OUT_LABELS + b * KMAX + rank] = (float)lab;
            out[OUT_SCORES + b * KMAX + rank] = sc;
        }
    }
}

extern "C" void kernel_launch(void* const* d_in, const int* in_sizes, int n_in,
                              void* d_out, int out_size, void* d_ws, size_t ws_size,
                              hipStream_t stream) {
    const float* locs   = (const float*)d_in[0];
    const float* scores = (const float*)d_in[1];
    const float* priors = (const float*)d_in[2];
    float* out = (float*)d_out;
    float* ws  = (float*)d_ws;

    det_softmax<<<(NB * NPRI + 255) / 256, 256, 0, stream>>>(scores, ws);
    det_prep<<<NB * NCLS, 256, 0, stream>>>(locs, priors, ws);
    det_mbuild<<<dim3((TMAX + 3) / 4, NB * NCLS), 256, 0, stream>>>(ws);
    det_finish<<<NB * NCLS, 256, 0, stream>>>(locs, priors, ws, out);
}

// Round 14
// 173.174 us; speedup vs baseline: 1.0375x; 1.0304x over previous
//
#include <hip/hip_runtime.h>

#define NB 4
#define NPRI 3106
#define NC 21
#define NCLS 20
#define KMAX 200
#define NMAX 1024   /* candidate capacity per (image,class) */
#define WMAX 16     /* NMAX/64 */
#define TMAX (WMAX*(WMAX+1)/2)   /* 136 triangular 64x64 tiles */
#define MIN_SC 0.05f
#define MAX_OV 0.45f

/* ---- workspace layout (float-element offsets; u64 arrays at even offsets) ---- */
#define F_PROBS 0                                  /* NB*NCLS*NPRI floats, [b][cls-1][p] */
#define F_KEYS  (F_PROBS + NB*NCLS*NPRI)           /* NB*NCLS*NMAX u64 (sorted keys)     */
#define F_BOXES (F_KEYS + NB*NCLS*NMAX*2)          /* NB*NCLS*NMAX float4 (sorted boxes) */
#define F_AREAS (F_BOXES + NB*NCLS*NMAX*4)         /* NB*NCLS*NMAX floats                */
#define F_NCAND (F_AREAS + NB*NCLS*NMAX)           /* NB*NCLS ints (pad to 128)          */
#define F_M     (F_NCAND + 128)                    /* NB*NCLS*WMAX*NMAX u64, [bc][w][j]  */
#define F_POOL  (F_M + NB*NCLS*WMAX*NMAX*2)        /* NB*NCLS*KMAX u64                   */
#define F_CNT   (F_POOL + NB*NCLS*KMAX*2)          /* NB*NCLS ints                       */
#define F_DONE  (F_CNT + NB*NCLS)                  /* NB ints (per-image done counters)  */

/* ---- output layout (floats) ---- */
#define OUT_BOXES  0
#define OUT_LABELS (NB*KMAX*4)
#define OUT_SCORES (OUT_LABELS + NB*KMAX)
#define OUT_COUNTS (OUT_SCORES + NB*KMAX)

__device__ __forceinline__ float bcast(float v, int l) {
    return __uint_as_float(__builtin_amdgcn_readlane(__float_as_uint(v), l));
}

__device__ __forceinline__ void decode_box(const float* __restrict__ locs,
                                           const float* __restrict__ priors,
                                           int b, int pi,
                                           float& x1, float& y1, float& x2, float& y2) {
    const float* l  = locs + ((size_t)b * NPRI + pi) * 4;
    const float* pr = priors + (size_t)pi * 4;
    float pcx = pr[0], pcy = pr[1], pw = pr[2], ph = pr[3];
    /* reference op order: (l*pw)/10 + pcx ; exp(l/5)*pw ; cx -/+ w/2 */
    float cx = l[0] * pw / 10.0f + pcx;
    float cy = l[1] * ph / 10.0f + pcy;
    float w  = expf(l[2] / 5.0f) * pw;
    float h  = expf(l[3] / 5.0f) * ph;
    x1 = cx - w / 2.0f;  y1 = cy - h / 2.0f;
    x2 = cx + w / 2.0f;  y2 = cy + h / 2.0f;
}

/* K0: softmax once per (b,p); coalesced stage via LDS (proven verbatim) */
__global__ __launch_bounds__(256)
void det_softmax(const float* __restrict__ scores, float* __restrict__ ws) {
    __shared__ float row[256 * NC];
    const int t0 = blockIdx.x * 256;
    int items = NB * NPRI - t0; if (items > 256) items = 256;
    const int cntf = items * NC;
    for (int i = threadIdx.x; i < cntf; i += 256)
        row[i] = scores[(size_t)t0 * NC + i];
    __syncthreads();
    const int t = t0 + threadIdx.x;
    if (t >= NB * NPRI) return;
    const int b = t / NPRI, p = t - b * NPRI;
    const float* s = row + threadIdx.x * NC;
    float m = -1e30f;
    #pragma unroll
    for (int c = 0; c < NC; ++c) m = fmaxf(m, s[c]);
    float e[NC]; float sum = 0.0f;
    #pragma unroll
    for (int c = 0; c < NC; ++c) { e[c] = expf(s[c] - m); sum += e[c]; }
    #pragma unroll
    for (int c = 1; c < NC; ++c)
        ws[F_PROBS + ((size_t)(b * NCLS + (c - 1)) * NPRI + p)] = e[c] / sum;
}

/* K1: per (image,class): compact > 0.05, bitonic sort, decode (proven verbatim) */
__global__ __launch_bounds__(256)
void det_prep(const float* __restrict__ locs, const float* __restrict__ priors,
              float* __restrict__ ws) {
    const int bc  = blockIdx.x;
    const int b   = bc / NCLS;
    const int tid = threadIdx.x;

    __shared__ unsigned long long keys[NMAX];   /* 8 KB */
    __shared__ int n_sh;
    if (tid == 0) n_sh = 0;
    __syncthreads();

    const float* prob = ws + F_PROBS + (size_t)bc * NPRI;
    for (int p = tid; p < NPRI; p += 256) {
        float s = prob[p];
        if (s > MIN_SC) {
            int idx = atomicAdd(&n_sh, 1);
            if (idx < NMAX) {
                unsigned int sb = __float_as_uint(s);
                keys[idx] = ((unsigned long long)(~sb) << 32) | (unsigned int)p;
            }
        }
    }
    __syncthreads();
    int n = n_sh; if (n > NMAX) n = NMAX;

    int npow = 1; while (npow < n) npow <<= 1;
    for (int i = n + tid; i < npow; i += 256) keys[i] = ~0ull;
    for (int k = 2; k <= npow; k <<= 1) {
        for (int j = k >> 1; j > 0; j >>= 1) {
            __syncthreads();
            for (int i = tid; i < npow; i += 256) {
                int ixj = i ^ j;
                if (ixj > i) {
                    unsigned long long a = keys[i], d = keys[ixj];
                    bool up = ((i & k) == 0);
                    if ((a > d) == up) { keys[i] = d; keys[ixj] = a; }
                }
            }
        }
    }
    __syncthreads();

    if (tid == 0) ((int*)(ws + F_NCAND))[bc] = n;
    unsigned long long* gk = (unsigned long long*)(ws + F_KEYS) + (size_t)bc * NMAX;
    float4* gb = (float4*)(ws + F_BOXES) + (size_t)bc * NMAX;
    float*  ga = ws + F_AREAS + (size_t)bc * NMAX;
    for (int i = tid; i < n; i += 256) {
        unsigned long long k = keys[i];
        gk[i] = k;
        int pi = (int)(k & 0xFFFFFFFFull);
        float x1, y1, x2, y2;
        decode_box(locs, priors, b, pi, x1, y1, x2, y2);
        gb[i] = make_float4(x1, y1, x2, y2);
        ga[i] = (x2 - x1) * (y2 - y1);
    }
}

/* K2 v3 (round-11 proven, 45.2 us): 64x64 tile per wave, 136 triangular tiles,
   TWO column-chains per unrolled step, divide-free with exact-div near band
   (bit-identical M). Issue-bound at ~75% VALUBusy; fatter tiles (R12) and
   4-chain ILP (R13) both measured slower — do not revisit without new evidence. */
__global__ __launch_bounds__(256)
void det_mbuild(float* __restrict__ ws) {
    if (blockIdx.x == 0 && blockIdx.y == 0 && threadIdx.x < NB)
        ((int*)(ws + F_DONE))[threadIdx.x] = 0;

    const int bc = blockIdx.y;
    const int t  = blockIdx.x * 4 + (threadIdx.x >> 6);
    if (t >= TMAX) return;
    const int lane = threadIdx.x & 63;
    int tj = 0;
    while ((tj + 1) * (tj + 2) / 2 <= t) ++tj;   /* wave-uniform decode */
    const int w = t - tj * (tj + 1) / 2;          /* w <= tj */
    const int n = ((const int*)(ws + F_NCAND))[bc];
    const int bi0 = w * 64, bj0 = tj * 64;
    if (bj0 >= n) return;

    const float4* bx = (const float4*)(ws + F_BOXES) + (size_t)bc * NMAX;
    const float*  ar = ws + F_AREAS + (size_t)bc * NMAX;
    const float4 bi = bx[bi0 + lane];
    const float  ai = ar[bi0 + lane];
    const float4 bj = bx[bj0 + lane];
    const float  aj = ar[bj0 + lane];
    const unsigned long long vm =
        (n - bi0 >= 64) ? ~0ull : ((1ull << (n - bi0)) - 1ull);
    const bool diag = (w == tj);
    unsigned long long myword = 0ull;

    #pragma unroll
    for (int jj = 0; jj < 64; jj += 2) {
        float ax1 = bcast(bj.x, jj),     ay1 = bcast(bj.y, jj);
        float ax2 = bcast(bj.z, jj),     ay2 = bcast(bj.w, jj);
        float aau = bcast(aj, jj);
        float bx1 = bcast(bj.x, jj + 1), by1 = bcast(bj.y, jj + 1);
        float bx2 = bcast(bj.z, jj + 1), by2 = bcast(bj.w, jj + 1);
        float bau = bcast(aj, jj + 1);

        float alx = fmaxf(bi.x, ax1), aly = fmaxf(bi.y, ay1);
        float arx = fminf(bi.z, ax2), ary = fminf(bi.w, ay2);
        float blx = fmaxf(bi.x, bx1), bly = fmaxf(bi.y, by1);
        float brx = fminf(bi.z, bx2), bry = fminf(bi.w, by2);
        float adx = fmaxf(arx - alx, 0.0f), ady = fmaxf(ary - aly, 0.0f);
        float bdx = fmaxf(brx - blx, 0.0f), bdy = fmaxf(bry - bly, 0.0f);
        float ain = adx * ady;
        float bin = bdx * bdy;
        float au  = ai + aau - ain;           /* union > 0 (areas positive) */
        float bu  = ai + bau - bin;
        float at  = MAX_OV * au;
        float bt  = MAX_OV * bu;
        bool akeep = ain > at;
        bool bkeep = bin > bt;
        bool anear = fabsf(ain - at) <= at * 6e-7f;
        bool bnear = fabsf(bin - bt) <= bt * 6e-7f;
        if (__ballot(anear || bnear)) {       /* rare: exact ref-order divide */
            float aio = ain / au;
            float bio = bin / bu;
            akeep = anear ? (aio > MAX_OV) : akeep;
            bkeep = bnear ? (bio > MAX_OV) : bkeep;
        }
        unsigned long long abits = __ballot(akeep) & vm;
        unsigned long long bbits = __ballot(bkeep) & vm;
        if (diag) {
            abits &= (1ull << jj) - 1ull;      /* i < j on diagonal tile */
            bbits &= (1ull << (jj + 1)) - 1ull;
        }
        if (lane == jj)     myword = abits;
        if (lane == jj + 1) myword = bbits;
    }
    if (bj0 + lane < n)
        ((unsigned long long*)(ws + F_M))
            [((size_t)bc * WMAX + w) * NMAX + bj0 + lane] = myword;
}

/* K3: resolve (wave 0 of 80 blocks) + zero-fill + release/acquire via done[b],
   then round-7 per-class rank-select topk (round-11 proven, verbatim). */
__global__ __launch_bounds__(256)
void det_finish(const float* __restrict__ locs, const float* __restrict__ priors,
                float* __restrict__ ws, float* __restrict__ out) {
    const int bc   = blockIdx.x;
    const int b    = bc / NCLS;
    const int c    = bc - b * NCLS;       /* 0..19 */
    const int cls  = c + 1;
    const int tid  = threadIdx.x;
    int* done_i = (int*)(ws + F_DONE);

    if (tid < 64) {
        const int lane = tid;
        const int n    = ((const int*)(ws + F_NCAND))[bc];
        const unsigned long long* Mb =
            (const unsigned long long*)(ws + F_M) + (size_t)bc * WMAX * NMAX;

        unsigned long long kw[WMAX];
        #pragma unroll
        for (int w = 0; w < WMAX; ++w) kw[w] = 0ull;

        const unsigned long long lmask = (1ull << lane) - 1ull;
        #pragma unroll
        for (int w = 0; w < WMAX; ++w) {
            if (w * 64 < n) {
                int cc = w * 64 + lane;
                bool valid = cc < n;
                unsigned long long pre = 0ull;
                #pragma unroll
                for (int v = 0; v < WMAX; ++v)
                    if (v < w) pre |= Mb[(size_t)v * NMAX + cc] & kw[v];
                unsigned long long dg = Mb[(size_t)w * NMAX + cc] & lmask;
                bool sup0 = (pre != 0ull);
                unsigned long long K = __ballot(valid && !sup0);
                for (int it = 0; it < 64; ++it) {
                    bool sup = sup0 || ((dg & K) != 0ull);
                    unsigned long long Kn = __ballot(valid && !sup);
                    if (Kn == K) break;
                    K = Kn;
                }
                kw[w] = K;
            }
        }

        int pref[WMAX + 1];
        pref[0] = 0;
        #pragma unroll
        for (int w = 0; w < WMAX; ++w) pref[w + 1] = pref[w] + __popcll(kw[w]);
        if (lane == 0) ((int*)(ws + F_CNT))[bc] = pref[WMAX];

        const unsigned long long* gk =
            (const unsigned long long*)(ws + F_KEYS) + (size_t)bc * NMAX;
        unsigned long long* pool =
            (unsigned long long*)(ws + F_POOL) + (size_t)bc * KMAX;
        const unsigned long long ctag = (unsigned long long)(cls << 12);
        #pragma unroll
        for (int w = 0; w < WMAX; ++w) {
            unsigned long long kwv = kw[w];
            int cc = w * 64 + lane;
            if (cc < n && ((kwv >> lane) & 1ull)) {
                int pos = pref[w] + __popcll(kwv & lmask);
                if (pos < KMAX) pool[pos] = gk[cc] | ctag;
            }
        }
    }

    /* zero image b's output slice, partitioned over its 20 blocks */
    {
        int idx = c * 256 + tid;
        if (idx < KMAX * 4) {
            out[OUT_BOXES + (size_t)b * KMAX * 4 + idx] = 0.0f;
        } else if (idx < KMAX * 4 + KMAX) {
            out[OUT_LABELS + b * KMAX + (idx - KMAX * 4)] = 0.0f;
        } else if (idx < KMAX * 4 + 2 * KMAX) {
            out[OUT_SCORES + b * KMAX + (idx - KMAX * 4 - KMAX)] = 0.0f;
        }
    }

    __threadfence();
    __syncthreads();
    if (tid == 0)
        __hip_atomic_fetch_add(done_i + b, 1, __ATOMIC_RELEASE,
                               __HIP_MEMORY_SCOPE_AGENT);

    if (tid == 0) {
        int it = 0;
        while (__hip_atomic_load(done_i + b, __ATOMIC_ACQUIRE,
                                 __HIP_MEMORY_SCOPE_AGENT) < NCLS
               && it < (1 << 20)) ++it;
    }
    __syncthreads();

    __shared__ unsigned long long lpool[NCLS * KMAX];  /* 32 KB */
    __shared__ int cnts[NCLS];

    const int* cnt = (const int*)(ws + F_CNT);
    if (tid < NCLS) cnts[tid] = cnt[b * NCLS + tid];
    __syncthreads();

    const unsigned long long* pool =
        (const unsigned long long*)(ws + F_POOL) + (size_t)b * NCLS * KMAX;
    for (int i = tid; i < NCLS * KMAX; i += 256) {
        int c2 = i / KMAX, r = i - c2 * KMAX;
        int mc2 = cnts[c2] < KMAX ? cnts[c2] : KMAX;
        lpool[i] = (r < mc2) ? pool[i] : ~0ull;
    }
    __syncthreads();

    if (c == 0 && tid == 0) {
        int tot = 0;
        for (int c2 = 0; c2 < NCLS; ++c2) tot += cnts[c2];
        int count = tot < KMAX ? tot : KMAX;
        if (tot == 0) {
            float* ob = out + OUT_BOXES + (size_t)b * KMAX * 4;
            ob[0] = 0.0f; ob[1] = 0.0f; ob[2] = 1.0f; ob[3] = 1.0f;
            count = 1;
        }
        out[OUT_COUNTS + b] = (float)count;
    }

    const int mc = cnts[c] < KMAX ? cnts[c] : KMAX;
    if (tid < mc) {
        unsigned long long key = lpool[c * KMAX + tid];
        int rank = 0;
        #pragma unroll
        for (int c2 = 0; c2 < NCLS; ++c2) {
            int lo = 0, hi = KMAX;
            #pragma unroll
            for (int s = 0; s < 8; ++s) {          /* ceil(log2(201)) = 8 */
                int mid = (lo + hi) >> 1;
                int midc = mid < KMAX ? mid : KMAX - 1;
                unsigned long long v = lpool[c2 * KMAX + midc];
                bool lt = (lo < hi) && (v < key);
                lo = lt ? mid + 1 : lo;
                hi = lt ? hi : mid;
            }
            rank += lo;
        }
        if (rank < KMAX) {
            unsigned int lo32 = (unsigned int)key;
            int pi  = lo32 & 0xFFF;
            int lab = (lo32 >> 12) & 0x1F;
            float sc = __uint_as_float(~(unsigned int)(key >> 32));
            float x1, y1, x2, y2;
            decode_box(locs, priors, b, pi, x1, y1, x2, y2);
            float* ob = out + OUT_BOXES + ((size_t)b * KMAX + rank) * 4;
            ob[0] = x1; ob[1] = y1; ob[2] = x2; ob[3] = y2;
            out[OUT_LABELS + b * KMAX + rank] = (float)lab;
            out[OUT_SCORES + b * KMAX + rank] = sc;
        }
    }
}

extern "C" void kernel_launch(void* const* d_in, const int* in_sizes, int n_in,
                              void* d_out, int out_size, void* d_ws, size_t ws_size,
                              hipStream_t stream) {
    const float* locs   = (const float*)d_in[0];
    const float* scores = (const float*)d_in[1];
    const float* priors = (const float*)d_in[2];
    float* out = (float*)d_out;
    float* ws  = (float*)d_ws;

    det_softmax<<<(NB * NPRI + 255) / 256, 256, 0, stream>>>(scores, ws);
    det_prep<<<NB * NCLS, 256, 0, stream>>>(locs, priors, ws);
    det_mbuild<<<dim3((TMAX + 3) / 4, NB * NCLS), 256, 0, stream>>>(ws);
    det_finish<<<NB * NCLS, 256, 0, stream>>>(locs, priors, ws, out);
}